// Round 19
// baseline (234.819 us; speedup 1.0000x reference)
//
#include <hip/hip_runtime.h>
#include <cstddef>

typedef unsigned short ushortT;
typedef short s8v __attribute__((ext_vector_type(8)));
typedef float f32x4 __attribute__((ext_vector_type(4)));

constexpr int NTOK = 2048;   // B*S
// packed tile: 16 cols x 160 k = 5 ks-steps x 512 elems = 2560 elems = 320 s8v

__device__ inline ushortT f2bf(float f) {
  unsigned u = __float_as_uint(f);
  u += 0x7fffu + ((u >> 16) & 1u);
  return (ushortT)(u >> 16);
}

// async global->LDS, 16B per lane; LDS base must be wave-uniform (linear layout only)
__device__ inline void gl_lds16(const s8v* g, s8v* l) {
  __builtin_amdgcn_global_load_lds(
      (const __attribute__((address_space(1))) unsigned int*)g,
      (__attribute__((address_space(3))) unsigned int*)l, 16, 0, 0);
}

// Device-scope grid barrier. SAFETY: requires all gridDim blocks co-resident —
// guaranteed here: launch_bounds(256,2) caps VGPR<=256 (2 waves/SIMD), LDS 53.5KB
// (2 blocks/CU), grid=512=2x256CU. Spin uses atomic RMW (atomicAdd(cnt,0)) which is
// device-coherent — a plain/volatile load could hit a stale per-XCD L2 line forever.
__device__ inline void grid_barrier(unsigned* cnt, unsigned target, int tid) {
  __syncthreads();                 // block's own work (incl. LDS) done
  if (tid == 0) {
    __threadfence();               // release: write back dirty L2 (cross-XCD visibility)
    atomicAdd(cnt, 1u);
    while (atomicAdd(cnt, 0u) < target) __builtin_amdgcn_s_sleep(2);
  }
  __syncthreads();
  __threadfence();                 // acquire: invalidate stale cache before reads
}

// Shared pack body: one 8-krow x 1024-col slab of W (or Wb/bb) -> fragment-major bf16.
// fac: 0/1 = permuted W-factor pack, 2 = WbP (unpermuted). lds >= 16KB.
__device__ inline void pack_slab(
    ushortT (*lds)[1024], int tid, int fac, int g, int jc8,
    const float* __restrict__ W, const float* __restrict__ bv,
    const float* __restrict__ Wb, const float* __restrict__ bb,
    ushortT* __restrict__ P)
{
  const int c4 = tid;                 // col-quad 0..255 (covers 1024 cols)
#pragma unroll
  for (int rl = 0; rl < 8; ++rl) {
    int jj = jc8 * 8 + rl;
    float4 v = make_float4(0.f, 0.f, 0.f, 0.f);
    if (fac < 2) {
      if (jj < 128)       v = *(const float4*)(W  + (size_t)jj * 32768 + g * 1024 + c4 * 4);
      else if (jj < 130)  v = *(const float4*)(bv + (size_t)(jj - 128) * 32768 + g * 1024 + c4 * 4);
    } else {
      if (jj < 128)       v = *(const float4*)(Wb + (size_t)(jj & 63) * 1024 + c4 * 4);
      else if (jj < 130)  v = *(const float4*)(bb + c4 * 4);
    }
    int col0 = c4 * 4;
    int sw = col0 ^ ((col0 >> 4) & 0x1C);   // bank swizzle (involution, keeps low 2 bits)
    ushortT* d = &lds[rl][sw];
    d[0] = f2bf(v.x); d[1] = f2bf(v.y); d[2] = f2bf(v.z); d[3] = f2bf(v.w);
  }
  __syncthreads();
  // rows jc8*8..+7  ->  ks = jc8>>2,  kkg = jc8&3
  const int ks = jc8 >> 2, kkg = jc8 & 3;
#pragma unroll
  for (int it = 0; it < 4; ++it) {
    int idx = tid + it * 256;          // 1024: ct_l(64) x cl(16)
    int ct_l = idx >> 4, cl = idx & 15;
    int scol;
    if (fac < 2) {
      int o = ct_l >> 1, ib = (ct_l & 1) * 16;
      scol = (ib + cl) * 32 + o;       // permute (g,i,o)->(g,o,i)
    } else {
      scol = ct_l * 16 + cl;
    }
    scol ^= ((scol >> 4) & 0x1C);
    ushortT v[8];
#pragma unroll
    for (int e = 0; e < 8; ++e) v[e] = lds[e][scol];
    size_t ctile = (fac < 2) ? (size_t)(g * 64 + ct_l) : (size_t)ct_l;
    size_t off = ctile * 2560 + (size_t)ks * 512 + (kkg * 16 + cl) * 8;
    uint4 qv;
    qv.x = v[0] | ((unsigned)v[1] << 16);
    qv.y = v[2] | ((unsigned)v[3] << 16);
    qv.z = v[4] | ((unsigned)v[5] << 16);
    qv.w = v[6] | ((unsigned)v[7] << 16);
    *(uint4*)(P + off) = qv;
  }
}

// ---------------- mm phase body (round-17 mm_kernel, verified) ----------------
// smem layout: bsh [2][1280] s8v @0 (40960B); xsf @40960 (8448B);
//              hs [64][8] @49408 (2048B); bls [64][8] @51456 (2048B). Total 53504B.
template <int PASS>
__device__ void mm_phase(
    char* smem, int tid, int bid,
    const s8v* __restrict__ fP, const s8v* __restrict__ wP,
    const s8v* __restrict__ wbP,
    const float* __restrict__ xg,    // pass1: x [t][1024]; pass2: h1T [1024][t]
    const float* __restrict__ rat,
    float* __restrict__ outp)        // pass1: h1T [1024][2048]; pass2: out [t][1024]
{
  s8v (*bsh)[1280] = (s8v (*)[1280])smem;
  float* xsf = (float*)(smem + 40960);            // p1: [64][33]; p2: [32][64]
  float (*hs)[8]  = (float (*)[8])(smem + 49408);
  float (*bls)[8] = (float (*)[8])(smem + 51456);

  const int lane = tid & 63;
  const int w = tid >> 6;
  const int cb  = (bid & 7) * 16 + (bid >> 5);  // 0..127 (XCD swizzle)
  const int tbgh = (bid >> 3) & 3;              // 0..3 (8 token-tiles each)
  const int g = cb >> 2;

  // A fragments (16 col-tiles per block, 4 per wave, 5 ks each) once into regs
  const s8v* ap = wP + (size_t)(cb * 16 + w * 4) * 320 + lane;
  s8v a[4][5];
#pragma unroll
  for (int i = 0; i < 4; ++i)
#pragma unroll
    for (int ks = 0; ks < 5; ++ks) a[i][ks] = ap[i * 320 + ks * 64];

  // bias A fragments (pass 2): col-tile cb>>1 of WbP
  s8v ab[5];
  if constexpr (PASS == 2) {
    const s8v* abp = wbP + (size_t)(cb >> 1) * 320 + lane;
#pragma unroll
    for (int ks = 0; ks < 5; ++ks) ab[ks] = abp[ks * 64];
  }

  // fP region for this block's 8 token-tiles: contiguous 8 x 1280 s8v
  const s8v* fbase = fP + (size_t)(tbgh * 8) * 1280;

  // prologue: DMA token-tile 0's B fragments (wave w stages subtile w: 5 x 64-lane chunks)
#pragma unroll
  for (int c2 = 0; c2 < 5; ++c2)
    gl_lds16(fbase + w * 320 + c2 * 64 + lane, &bsh[0][w * 320 + c2 * 64]);
  __syncthreads();   // compiler drains vmcnt before barrier

#pragma unroll 1
  for (int tt2 = 0; tt2 < 8; ++tt2) {
    const int buf = tt2 & 1;
    const int t0 = (tbgh * 8 + tt2) * 64;

    // multiplier loads first (consumed after K-loop)
    float4 xv[2];
#pragma unroll
    for (int it = 0; it < 2; ++it) {
      int idx = tid + it * 256;          // 512 loads
      if (PASS == 1) {
        int t = idx >> 3, i4 = idx & 7;  // [t][i4*4] from x
        xv[it] = *(const float4*)(xg + (size_t)(t0 + t) * 1024 + g * 32 + i4 * 4);
      } else {
        int i = idx >> 4, tq = idx & 15; // row i*32+g of h1T, 4 consecutive t
        xv[it] = *(const float4*)(xg + (size_t)(i * 32 + g) * 2048 + t0 + tq * 4);
      }
    }
    // prefetch next tile's B via DMA (completes by barrier A)
    if (tt2 < 7) {
      const s8v* fn = fbase + (size_t)(tt2 + 1) * 1280;
#pragma unroll
      for (int c2 = 0; c2 < 5; ++c2)
        gl_lds16(fn + w * 320 + c2 * 64 + lane, &bsh[buf ^ 1][w * 320 + c2 * 64]);
    }

    f32x4 acc[4][4];
#pragma unroll
    for (int i = 0; i < 4; ++i)
#pragma unroll
      for (int j = 0; j < 4; ++j) acc[i][j] = {0.f, 0.f, 0.f, 0.f};
    f32x4 accb = {0.f, 0.f, 0.f, 0.f};

    __builtin_amdgcn_s_setprio(1);
#pragma unroll
    for (int ks = 0; ks < 5; ++ks) {
      s8v b0 = bsh[buf][0 * 320 + ks * 64 + lane];
      s8v b1 = bsh[buf][1 * 320 + ks * 64 + lane];
      s8v b2v = bsh[buf][2 * 320 + ks * 64 + lane];
      s8v b3 = bsh[buf][3 * 320 + ks * 64 + lane];
      if constexpr (PASS == 2) {  // wave's own subtile via LDS address arith (rule #20 safe)
        s8v bw = bsh[buf][w * 320 + ks * 64 + lane];
        accb = __builtin_amdgcn_mfma_f32_16x16x32_bf16(ab[ks], bw, accb, 0, 0, 0);
      }
#pragma unroll
      for (int i = 0; i < 4; ++i) {
        acc[i][0] = __builtin_amdgcn_mfma_f32_16x16x32_bf16(a[i][ks], b0,  acc[i][0], 0, 0, 0);
        acc[i][1] = __builtin_amdgcn_mfma_f32_16x16x32_bf16(a[i][ks], b1,  acc[i][1], 0, 0, 0);
        acc[i][2] = __builtin_amdgcn_mfma_f32_16x16x32_bf16(a[i][ks], b2v, acc[i][2], 0, 0, 0);
        acc[i][3] = __builtin_amdgcn_mfma_f32_16x16x32_bf16(a[i][ks], b3,  acc[i][3], 0, 0, 0);
      }
    }
    __builtin_amdgcn_s_setprio(0);

    // write xs (single buffer: previous tile's readers finished before its barrier B)
#pragma unroll
    for (int it = 0; it < 2; ++it) {
      int idx = tid + it * 256;
      float* d;
      if (PASS == 1) { int t = idx >> 3, i4 = idx & 7; d = &xsf[t * 33 + i4 * 4]; }
      else           { int i = idx >> 4, tq = idx & 15; d = &xsf[i * 64 + tq * 4]; }
      d[0] = xv[it].x; d[1] = xv[it].y; d[2] = xv[it].z; d[3] = xv[it].w;
    }
    __syncthreads();   // A: xs ready; next-tile DMA drained into bsh[buf^1]

    const int tau = lane & 15, q = lane >> 4;
#pragma unroll
    for (int tt = 0; tt < 4; ++tt) {
      int tl = tt * 16 + tau;
#pragma unroll
      for (int run = 0; run < 2; ++run) {
        float sacc = 0.f;
#pragma unroll
        for (int ch = 0; ch < 2; ++ch) {
          int ct = run * 2 + ch;
          f32x4 av = acc[ct][tt];
#pragma unroll
          for (int r = 0; r < 4; ++r) {
            int i = ch * 16 + q * 4 + r;
            float xvv = (PASS == 1) ? xsf[tl * 33 + i] : xsf[i * 64 + tl];
            sacc = fmaf(av[r], xvv, sacc);
          }
        }
        sacc += __shfl_xor(sacc, 16);
        sacc += __shfl_xor(sacc, 32);
        if constexpr (PASS == 1) {
          // direct 64B-coalesced store: h1T[colg][t0+tt*16+tau], col8 = w*2+run
          if (lane < 16) {
            int colg = g * 32 + (cb & 3) * 8 + w * 2 + run;
            outp[(size_t)colg * 2048 + t0 + tt * 16 + tau] = sacc;
          }
        } else {
          if (lane < 16) hs[tl][w * 2 + run] = sacc;
        }
      }
    }
    if constexpr (PASS == 2) {
      // accb rows (bias col-in-tile) = q*4+r; keep rows [ (cb&1)*8, +8 )
      if ((lane >> 5) == (cb & 1)) {
        int ol = ((lane >> 4) & 1) * 4;
#pragma unroll
        for (int r = 0; r < 4; ++r) bls[w * 16 + tau][ol + r] = accb[r];
      }
      __syncthreads();   // B: hs/bls ready (also fences xsf reuse next tile)
      if (tid < 128) {
        int row = tid >> 1, half = tid & 1;
        int t = t0 + row;
        int col = g * 32 + (cb & 3) * 8 + half * 4;
        float r = rat[t];
        float4 o;
        o.x = fmaf(hs[row][half * 4 + 0], r, bls[row][half * 4 + 0]);
        o.y = fmaf(hs[row][half * 4 + 1], r, bls[row][half * 4 + 1]);
        o.z = fmaf(hs[row][half * 4 + 2], r, bls[row][half * 4 + 2]);
        o.w = fmaf(hs[row][half * 4 + 3], r, bls[row][half * 4 + 3]);
        *(float4*)(outp + (size_t)t * 1024 + col) = o;
      }
    } else {
      __syncthreads();   // B: xsf readers done before next tile's writers (single buffer)
    }
  }
}

// ---------------- fused kernel: prep+pack | grid-barrier | mm1 | grid-barrier | mm2 ----
__global__ __launch_bounds__(256, 2) void fused_kernel(
    const float* __restrict__ x, const float* __restrict__ Wc, const float* __restrict__ bc,
    const float* __restrict__ Wm, const float* __restrict__ bm,
    const float* __restrict__ Wr, const float* __restrict__ br,
    const float* __restrict__ W1, const float* __restrict__ b1,
    const float* __restrict__ W2, const float* __restrict__ b2,
    const float* __restrict__ Wb, const float* __restrict__ bb,
    ushortT* __restrict__ FP, float* __restrict__ ratio,
    ushortT* __restrict__ P1, ushortT* __restrict__ P2, ushortT* __restrict__ WbP,
    float* __restrict__ h1T, float* __restrict__ out, unsigned* __restrict__ bar)
{
  __shared__ __align__(16) char smem[53504];
  const int tid = threadIdx.x;
  const int bid = blockIdx.x;

  // ================= phase 0a: prep (tokens bid*4 .. +3) =================
  {
    float* part = (float*)smem;          // [4 waves][4 tok][64] = 4KB
    float* cf_s = part + 1024;           // [4][64]
    float* a0s  = cf_s + 256;            // [4]
    float* a1s  = a0s + 4;               // [4]
    const int c = tid & 63;
    const int q = tid >> 6;
    const int t0 = bid * 4;

    float acc[4];
#pragma unroll
    for (int p = 0; p < 4; ++p) acc[p] = 0.f;
    const float* xq = x + (size_t)t0 * 1024 + q * 256;
    const float* wq = Wc + (size_t)(q * 256) * 64 + c;
#pragma unroll 4
    for (int jj = 0; jj < 64; ++jj) {
      float w0 = wq[(jj * 4 + 0) * 64];
      float w1 = wq[(jj * 4 + 1) * 64];
      float w2 = wq[(jj * 4 + 2) * 64];
      float w3 = wq[(jj * 4 + 3) * 64];
#pragma unroll
      for (int p = 0; p < 4; ++p) {
        float4 xv = *(const float4*)(xq + (size_t)p * 1024 + jj * 4);
        acc[p] = fmaf(xv.x, w0, acc[p]);
        acc[p] = fmaf(xv.y, w1, acc[p]);
        acc[p] = fmaf(xv.z, w2, acc[p]);
        acc[p] = fmaf(xv.w, w3, acc[p]);
      }
    }
#pragma unroll
    for (int p = 0; p < 4; ++p) part[(q * 4 + p) * 64 + c] = acc[p];
    __syncthreads();

    {
      int p = tid >> 6, cc = tid & 63;   // 256 threads = 4 tok x 64 c
      float s = part[(0 + p) * 64 + cc] + part[(4 + p) * 64 + cc] +
                part[(8 + p) * 64 + cc] + part[(12 + p) * 64 + cc] + bc[cc];
      cf_s[p * 64 + cc] = tanhf(s);
    }
    __syncthreads();

    {
      // softmax + ratio: wave q owns token q
      float cf = cf_s[q * 64 + c];
      float z0 = cf * Wm[2 * c], z1 = cf * Wm[2 * c + 1], rr = cf * Wr[c];
      for (int off = 32; off; off >>= 1) {
        z0 += __shfl_down(z0, off);
        z1 += __shfl_down(z1, off);
        rr += __shfl_down(rr, off);
      }
      if (c == 0) {
        z0 += bm[0]; z1 += bm[1];
        float mx = fmaxf(z0, z1);
        float e0 = expf(z0 - mx), e1 = expf(z1 - mx);
        float a0 = e0 / (e0 + e1);
        a0s[q] = a0;
        a1s[q] = 1.0f - a0;
        ratio[t0 + q] = rr + br[0];
      }
    }
    __syncthreads();

    // pack f fragments (wave q owns token q):
    // elem = tt*2560 + ks*512 + ((kk>>3)*16 + tok)*8 + (kk&7)
    const int ks0 = c >> 5, kk = c & 31;
    const int slot = (kk >> 3) * 16, e = kk & 7;
    {
      int t = t0 + q, tt = t >> 4, tok = t & 15;
      size_t base = (size_t)tt * 2560;
      float cf = cf_s[q * 64 + c];
      float a0 = a0s[q], a1 = a1s[q];
      FP[base + (size_t)ks0 * 512 + (slot + tok) * 8 + e]       = f2bf(a0 * cf);
      FP[base + (size_t)(2 + ks0) * 512 + (slot + tok) * 8 + e] = f2bf(a1 * cf);
      if (c < 32) {
        float v = (c == 0) ? a0 : (c == 1) ? a1 : 0.0f;
        FP[base + 4 * 512 + ((c >> 3) * 16 + tok) * 8 + (c & 7)] = f2bf(v);
      }
    }
  }
  __syncthreads();   // prep LDS reads done before pack overwrites smem

  // ================= phase 0b: pack slabs {bid, bid+512, bid+1024<1300} =================
  {
    ushortT (*lds)[1024] = (ushortT (*)[1024])smem;   // 16KB
#pragma unroll 1
    for (int si = 0; si < 3; ++si) {
      int s = bid + si * 512;
      if (s >= 1300) break;
      int fac, g, jc8;
      if (s < 640)       { fac = 0; g = s / 20; jc8 = s % 20; }
      else if (s < 1280) { fac = 1; int r = s - 640; g = r / 20; jc8 = r % 20; }
      else               { fac = 2; g = 0; jc8 = s - 1280; }
      const float* W  = (fac == 0) ? W1 : W2;
      const float* bv = (fac == 0) ? b1 : b2;
      ushortT* P = (fac == 0) ? P1 : (fac == 1) ? P2 : WbP;
      pack_slab(lds, tid, fac, g, jc8, W, bv, Wb, bb, P);
      __syncthreads();   // slab n's LDS readers done before slab n+1's writers
    }
  }

  grid_barrier(bar + 0, 512, tid);   // FP/P1/P2/WbP/ratio visible device-wide

  mm_phase<1>(smem, tid, bid, (const s8v*)FP, (const s8v*)P1, (const s8v*)WbP,
              x, nullptr, h1T);

  grid_barrier(bar + 1, 512, tid);   // h1T visible device-wide

  mm_phase<2>(smem, tid, bid, (const s8v*)FP, (const s8v*)P2, (const s8v*)WbP,
              h1T, ratio, out);
}

extern "C" void kernel_launch(void* const* d_in, const int* in_sizes, int n_in,
                              void* d_out, int out_size, void* d_ws, size_t ws_size,
                              hipStream_t stream) {
  const float* x  = (const float*)d_in[0];
  const float* Wc = (const float*)d_in[1];
  const float* bc = (const float*)d_in[2];
  const float* W1 = (const float*)d_in[3];
  const float* b1 = (const float*)d_in[4];
  const float* W2 = (const float*)d_in[5];
  const float* b2 = (const float*)d_in[6];
  const float* Wm = (const float*)d_in[7];
  const float* bm = (const float*)d_in[8];
  const float* Wb = (const float*)d_in[9];
  const float* bb = (const float*)d_in[10];
  const float* Wr = (const float*)d_in[11];
  const float* br = (const float*)d_in[12];
  float* out = (float*)d_out;

  // workspace carve-up
  ushortT* P1  = (ushortT*)d_ws;                        // 2048*2560 bf16
  ushortT* P2  = P1 + (size_t)2048 * 2560;              // 2048*2560 bf16
  ushortT* WbP = P2 + (size_t)2048 * 2560;              // 64*2560 bf16
  ushortT* FP  = WbP + (size_t)64 * 2560;               // 128*2560 bf16
  float* ratio = (float*)(FP + (size_t)128 * 2560);     // 2048
  float* h1T   = ratio + NTOK;                          // 1024*2048 (col-major h1)
  unsigned* bar = (unsigned*)(h1T + (size_t)1024 * 2048);  // 2 barrier counters

  hipMemsetAsync(bar, 0, 2 * sizeof(unsigned), stream);
  fused_kernel<<<dim3(512), dim3(256), 0, stream>>>(
      x, Wc, bc, Wm, bm, Wr, br, W1, b1, W2, b2, Wb, bb,
      FP, ratio, P1, P2, WbP, h1T, out, bar);
}

// Round 20
// 77.013 us; speedup vs baseline: 3.0491x; 3.0491x over previous
//
#include <hip/hip_runtime.h>
#include <cstddef>

typedef unsigned short ushortT;
typedef short s8v __attribute__((ext_vector_type(8)));
typedef float f32x4 __attribute__((ext_vector_type(4)));

constexpr int NTOK = 2048;   // B*S
// packed tile: 16 cols x 160 k = 5 ks-steps x 512 elems = 2560 elems = 320 s8v

__device__ inline ushortT f2bf(float f) {
  unsigned u = __float_as_uint(f);
  u += 0x7fffu + ((u >> 16) & 1u);
  return (ushortT)(u >> 16);
}

// async global->LDS, 16B per lane; LDS base must be wave-uniform (linear layout only)
__device__ inline void gl_lds16(const s8v* g, s8v* l) {
  __builtin_amdgcn_global_load_lds(
      (const __attribute__((address_space(1))) unsigned int*)g,
      (__attribute__((address_space(3))) unsigned int*)l, 16, 0, 0);
}

// ---------------- setup: prep (blocks 0..511) + pack_w (blocks 512..1811) ----------------
// prep: 512x4 tokens (wave q owns token q). pack: 8 k-rows x 1024 cols per block.
__global__ __launch_bounds__(256) void setup_kernel(
    const float* __restrict__ x, const float* __restrict__ Wc, const float* __restrict__ bc,
    const float* __restrict__ Wm, const float* __restrict__ bm,
    const float* __restrict__ Wr, const float* __restrict__ br,
    const float* __restrict__ W1, const float* __restrict__ b1,
    const float* __restrict__ W2, const float* __restrict__ b2,
    const float* __restrict__ Wb, const float* __restrict__ bb,
    ushortT* __restrict__ FP, float* __restrict__ ratio,
    ushortT* __restrict__ P1, ushortT* __restrict__ P2, ushortT* __restrict__ WbP)
{
  __shared__ __align__(16) char smem[16384];
  const int tid = threadIdx.x;
  const int bid = blockIdx.x;

  if (bid < 512) {
    // ================= prep: 4 tokens/block =================
    float* part = (float*)smem;          // [4 waves][4 tok][64] = 4KB
    float* cf_s = part + 1024;           // [4][64]
    float* a0s  = cf_s + 256;            // [4]
    float* a1s  = a0s + 4;               // [4]
    const int c = tid & 63;
    const int q = tid >> 6;
    const int t0 = bid * 4;

    float acc[4];
#pragma unroll
    for (int p = 0; p < 4; ++p) acc[p] = 0.f;
    const float* xq = x + (size_t)t0 * 1024 + q * 256;
    const float* wq = Wc + (size_t)(q * 256) * 64 + c;
#pragma unroll 4
    for (int jj = 0; jj < 64; ++jj) {
      float w0 = wq[(jj * 4 + 0) * 64];
      float w1 = wq[(jj * 4 + 1) * 64];
      float w2 = wq[(jj * 4 + 2) * 64];
      float w3 = wq[(jj * 4 + 3) * 64];
#pragma unroll
      for (int p = 0; p < 4; ++p) {
        float4 xv = *(const float4*)(xq + (size_t)p * 1024 + jj * 4);
        acc[p] = fmaf(xv.x, w0, acc[p]);
        acc[p] = fmaf(xv.y, w1, acc[p]);
        acc[p] = fmaf(xv.z, w2, acc[p]);
        acc[p] = fmaf(xv.w, w3, acc[p]);
      }
    }
#pragma unroll
    for (int p = 0; p < 4; ++p) part[(q * 4 + p) * 64 + c] = acc[p];
    __syncthreads();

    {
      int p = tid >> 6, cc = tid & 63;   // 256 threads = 4 tok x 64 c
      float s = part[(0 + p) * 64 + cc] + part[(4 + p) * 64 + cc] +
                part[(8 + p) * 64 + cc] + part[(12 + p) * 64 + cc] + bc[cc];
      cf_s[p * 64 + cc] = tanhf(s);
    }
    __syncthreads();

    {
      // softmax + ratio: wave q owns token q
      float cf = cf_s[q * 64 + c];
      float z0 = cf * Wm[2 * c], z1 = cf * Wm[2 * c + 1], rr = cf * Wr[c];
      for (int off = 32; off; off >>= 1) {
        z0 += __shfl_down(z0, off);
        z1 += __shfl_down(z1, off);
        rr += __shfl_down(rr, off);
      }
      if (c == 0) {
        z0 += bm[0]; z1 += bm[1];
        float mx = fmaxf(z0, z1);
        float e0 = expf(z0 - mx), e1 = expf(z1 - mx);
        float a0 = e0 / (e0 + e1);
        a0s[q] = a0;
        a1s[q] = 1.0f - a0;
        ratio[t0 + q] = rr + br[0];
      }
    }
    __syncthreads();

    // pack f fragments (wave q owns token q):
    // elem = tt*2560 + ks*512 + ((kk>>3)*16 + tok)*8 + (kk&7)
    const int ks0 = c >> 5, kk = c & 31;
    const int slot = (kk >> 3) * 16, e = kk & 7;
    {
      int t = t0 + q, tt = t >> 4, tok = t & 15;
      size_t base = (size_t)tt * 2560;
      float cf = cf_s[q * 64 + c];
      float a0 = a0s[q], a1 = a1s[q];
      FP[base + (size_t)ks0 * 512 + (slot + tok) * 8 + e]       = f2bf(a0 * cf);
      FP[base + (size_t)(2 + ks0) * 512 + (slot + tok) * 8 + e] = f2bf(a1 * cf);
      if (c < 32) {
        float v = (c == 0) ? a0 : (c == 1) ? a1 : 0.0f;
        FP[base + 4 * 512 + ((c >> 3) * 16 + tok) * 8 + (c & 7)] = f2bf(v);
      }
    }
  } else {
    // ================= pack_w: 8 k-rows x 1024 cols per block =================
    ushortT (*lds)[1024] = (ushortT (*)[1024])smem;   // [8][1024] = 16KB
    int pb = bid - 512;
    int fac, g, jc8;
    if (pb < 1280) { fac = pb / 640; int rem = pb % 640; g = rem / 20; jc8 = rem % 20; }
    else           { fac = 2; g = 0; jc8 = pb - 1280; }
    const float* W  = (fac == 0) ? W1 : W2;
    const float* bv = (fac == 0) ? b1 : b2;
    ushortT* P = (fac == 0) ? P1 : (fac == 1) ? P2 : WbP;
    const int c4 = tid;                 // col-quad 0..255 (covers 1024 cols)

#pragma unroll
    for (int rl = 0; rl < 8; ++rl) {
      int jj = jc8 * 8 + rl;
      float4 v = make_float4(0.f, 0.f, 0.f, 0.f);
      if (fac < 2) {
        if (jj < 128)       v = *(const float4*)(W  + (size_t)jj * 32768 + g * 1024 + c4 * 4);
        else if (jj < 130)  v = *(const float4*)(bv + (size_t)(jj - 128) * 32768 + g * 1024 + c4 * 4);
      } else {
        if (jj < 128)       v = *(const float4*)(Wb + (size_t)(jj & 63) * 1024 + c4 * 4);
        else if (jj < 130)  v = *(const float4*)(bb + c4 * 4);
      }
      int col0 = c4 * 4;
      int sw = col0 ^ ((col0 >> 4) & 0x1C);   // bank swizzle (involution, keeps low 2 bits)
      ushortT* d = &lds[rl][sw];
      d[0] = f2bf(v.x); d[1] = f2bf(v.y); d[2] = f2bf(v.z); d[3] = f2bf(v.w);
    }
    __syncthreads();
    // rows jc8*8..+7  ->  ks = jc8>>2,  kkg = jc8&3
    const int ks = jc8 >> 2, kkg = jc8 & 3;
#pragma unroll
    for (int it = 0; it < 4; ++it) {
      int idx = tid + it * 256;          // 1024: ct_l(64) x cl(16)
      int ct_l = idx >> 4, cl = idx & 15;
      int scol;
      if (fac < 2) {
        int o = ct_l >> 1, ib = (ct_l & 1) * 16;
        scol = (ib + cl) * 32 + o;       // permute (g,i,o)->(g,o,i)
      } else {
        scol = ct_l * 16 + cl;
      }
      scol ^= ((scol >> 4) & 0x1C);
      ushortT v[8];
#pragma unroll
      for (int e = 0; e < 8; ++e) v[e] = lds[e][scol];
      size_t ctile = (fac < 2) ? (size_t)(g * 64 + ct_l) : (size_t)ct_l;
      size_t off = ctile * 2560 + (size_t)ks * 512 + (kkg * 16 + cl) * 8;
      uint4 qv;
      qv.x = v[0] | ((unsigned)v[1] << 16);
      qv.y = v[2] | ((unsigned)v[3] << 16);
      qv.z = v[4] | ((unsigned)v[5] << 16);
      qv.w = v[6] | ((unsigned)v[7] << 16);
      *(uint4*)(P + off) = qv;
    }
  }
}

// ---------------- MFMA GEMM + fused monarch reduction (+ fused bias in pass 2) --------
// Grid 512 (= exactly 2 blocks/CU x 256 CUs); 8 token-tiles per block (A-frags reused 8x);
// setprio(1) around the MFMA cluster; pass1 direct h1T stores (1 barrier/tile, xsf dbuf).
// bid decode: cb = (bid&7)*16 + (bid>>5) (XCD swizzle), tbgh = (bid>>3)&3.
template <int PASS>
__global__ __launch_bounds__(256, 2) void mm_kernel(
    const s8v* __restrict__ fP, const s8v* __restrict__ wP,
    const s8v* __restrict__ wbP,
    const float* __restrict__ xg,    // pass1: x [t][1024]; pass2: h1T [1024][t]
    const float* __restrict__ rat,
    float* __restrict__ outp)        // pass1: h1T [1024][2048]; pass2: out [t][1024]
{
  __shared__ s8v bsh[2][1280];       // 2 x 20KB B-fragment stage (DMA dest, linear)
  __shared__ float xsf[(PASS == 1 ? 2 : 1) * 2112];  // p1: 2x[64 t][33]; p2: [32 i][66]
  __shared__ float hs[PASS == 2 ? 64 : 1][9];
  __shared__ float bls[PASS == 2 ? 64 : 1][9];
  const int tid = threadIdx.x;
  const int lane = tid & 63;
  const int w = tid >> 6;
  const int bid = blockIdx.x;                   // 0..511
  const int cb  = (bid & 7) * 16 + (bid >> 5);  // 0..127 (XCD swizzle)
  const int tbgh = (bid >> 3) & 3;              // 0..3 (8 token-tiles each)
  const int g = cb >> 2;

  // A fragments (16 col-tiles per block, 4 per wave, 5 ks each) once into regs
  const s8v* ap = wP + (size_t)(cb * 16 + w * 4) * 320 + lane;
  s8v a[4][5];
#pragma unroll
  for (int i = 0; i < 4; ++i)
#pragma unroll
    for (int ks = 0; ks < 5; ++ks) a[i][ks] = ap[i * 320 + ks * 64];

  // bias A fragments (pass 2): col-tile cb>>1 of WbP
  s8v ab[5];
  if constexpr (PASS == 2) {
    const s8v* abp = wbP + (size_t)(cb >> 1) * 320 + lane;
#pragma unroll
    for (int ks = 0; ks < 5; ++ks) ab[ks] = abp[ks * 64];
  }

  // fP region for this block's 8 token-tiles: contiguous 8 x 1280 s8v
  const s8v* fbase = fP + (size_t)(tbgh * 8) * 1280;

  // prologue: DMA token-tile 0's B fragments (wave w stages its 5 x 64-lane chunks)
#pragma unroll
  for (int c2 = 0; c2 < 5; ++c2)
    gl_lds16(fbase + w * 320 + c2 * 64 + lane, &bsh[0][w * 320 + c2 * 64]);
  __syncthreads();   // compiler drains vmcnt before barrier

#pragma unroll 1
  for (int tt2 = 0; tt2 < 8; ++tt2) {
    const int buf = tt2 & 1;
    const int t0 = (tbgh * 8 + tt2) * 64;

    // multiplier loads first (consumed after K-loop)
    float4 xv[2];
#pragma unroll
    for (int it = 0; it < 2; ++it) {
      int idx = tid + it * 256;          // 512 loads
      if (PASS == 1) {
        int t = idx >> 3, i4 = idx & 7;  // [t][i4*4] from x
        xv[it] = *(const float4*)(xg + (size_t)(t0 + t) * 1024 + g * 32 + i4 * 4);
      } else {
        int i = idx >> 4, tq = idx & 15; // row i*32+g of h1T, 4 consecutive t
        xv[it] = *(const float4*)(xg + (size_t)(i * 32 + g) * 2048 + t0 + tq * 4);
      }
    }
    // prefetch next tile's B via DMA (completes by barrier A)
    if (tt2 < 7) {
      const s8v* fn = fbase + (size_t)(tt2 + 1) * 1280;
#pragma unroll
      for (int c2 = 0; c2 < 5; ++c2)
        gl_lds16(fn + w * 320 + c2 * 64 + lane, &bsh[buf ^ 1][w * 320 + c2 * 64]);
    }

    f32x4 acc[4][4];
#pragma unroll
    for (int i = 0; i < 4; ++i)
#pragma unroll
      for (int j = 0; j < 4; ++j) acc[i][j] = {0.f, 0.f, 0.f, 0.f};
    f32x4 accb = {0.f, 0.f, 0.f, 0.f};

    __builtin_amdgcn_s_setprio(1);
#pragma unroll
    for (int ks = 0; ks < 5; ++ks) {
      s8v b0 = bsh[buf][0 * 320 + ks * 64 + lane];
      s8v b1 = bsh[buf][1 * 320 + ks * 64 + lane];
      s8v b2 = bsh[buf][2 * 320 + ks * 64 + lane];
      s8v b3 = bsh[buf][3 * 320 + ks * 64 + lane];
      if constexpr (PASS == 2) {  // wave's own subtile via LDS address arith (rule #20 safe)
        s8v bw = bsh[buf][w * 320 + ks * 64 + lane];
        accb = __builtin_amdgcn_mfma_f32_16x16x32_bf16(ab[ks], bw, accb, 0, 0, 0);
      }
#pragma unroll
      for (int i = 0; i < 4; ++i) {
        acc[i][0] = __builtin_amdgcn_mfma_f32_16x16x32_bf16(a[i][ks], b0, acc[i][0], 0, 0, 0);
        acc[i][1] = __builtin_amdgcn_mfma_f32_16x16x32_bf16(a[i][ks], b1, acc[i][1], 0, 0, 0);
        acc[i][2] = __builtin_amdgcn_mfma_f32_16x16x32_bf16(a[i][ks], b2, acc[i][2], 0, 0, 0);
        acc[i][3] = __builtin_amdgcn_mfma_f32_16x16x32_bf16(a[i][ks], b3, acc[i][3], 0, 0, 0);
      }
    }
    __builtin_amdgcn_s_setprio(0);

    // write xs
#pragma unroll
    for (int it = 0; it < 2; ++it) {
      int idx = tid + it * 256;
      float* d;
      if (PASS == 1) { int t = idx >> 3, i4 = idx & 7; d = &xsf[buf * 2112 + t * 33 + i4 * 4]; }
      else           { int i = idx >> 4, tq = idx & 15; d = &xsf[i * 66 + tq * 4]; }
      d[0] = xv[it].x; d[1] = xv[it].y; d[2] = xv[it].z; d[3] = xv[it].w;
    }
    __syncthreads();   // A: xs ready; next-tile DMA drained into bsh[buf^1]

    const int tau = lane & 15, q = lane >> 4;
#pragma unroll
    for (int tt = 0; tt < 4; ++tt) {
      int tl = tt * 16 + tau;
#pragma unroll
      for (int run = 0; run < 2; ++run) {
        float sacc = 0.f;
#pragma unroll
        for (int ch = 0; ch < 2; ++ch) {
          int ct = run * 2 + ch;
          f32x4 av = acc[ct][tt];
#pragma unroll
          for (int r = 0; r < 4; ++r) {
            int i = ch * 16 + q * 4 + r;
            float xvv = (PASS == 1) ? xsf[buf * 2112 + tl * 33 + i] : xsf[i * 66 + tl];
            sacc = fmaf(av[r], xvv, sacc);
          }
        }
        sacc += __shfl_xor(sacc, 16);
        sacc += __shfl_xor(sacc, 32);
        if constexpr (PASS == 1) {
          // direct 64B-coalesced store: h1T[colg][t0+tt*16+tau], col8 = w*2+run
          if (lane < 16) {
            int colg = g * 32 + (cb & 3) * 8 + w * 2 + run;
            outp[(size_t)colg * 2048 + t0 + tt * 16 + tau] = sacc;
          }
        } else {
          if (lane < 16) hs[tl][w * 2 + run] = sacc;
        }
      }
    }
    if constexpr (PASS == 2) {
      // accb rows (bias col-in-tile) = q*4+r; keep rows [ (cb&1)*8, +8 )
      if ((lane >> 5) == (cb & 1)) {
        int ol = ((lane >> 4) & 1) * 4;
#pragma unroll
        for (int r = 0; r < 4; ++r) bls[w * 16 + tau][ol + r] = accb[r];
      }
      __syncthreads();   // B: hs/bls ready
      if (tid < 128) {
        int row = tid >> 1, half = tid & 1;
        int t = t0 + row;
        int col = g * 32 + (cb & 3) * 8 + half * 4;
        float r = rat[t];
        float4 o;
        o.x = fmaf(hs[row][half * 4 + 0], r, bls[row][half * 4 + 0]);
        o.y = fmaf(hs[row][half * 4 + 1], r, bls[row][half * 4 + 1]);
        o.z = fmaf(hs[row][half * 4 + 2], r, bls[row][half * 4 + 2]);
        o.w = fmaf(hs[row][half * 4 + 3], r, bls[row][half * 4 + 3]);
        *(float4*)(outp + (size_t)t * 1024 + col) = o;
      }
    }
    // pass1: no barrier B — xsf double-buffer fences the only cross-tile LDS reuse
  }
}

extern "C" void kernel_launch(void* const* d_in, const int* in_sizes, int n_in,
                              void* d_out, int out_size, void* d_ws, size_t ws_size,
                              hipStream_t stream) {
  const float* x  = (const float*)d_in[0];
  const float* Wc = (const float*)d_in[1];
  const float* bc = (const float*)d_in[2];
  const float* W1 = (const float*)d_in[3];
  const float* b1 = (const float*)d_in[4];
  const float* W2 = (const float*)d_in[5];
  const float* b2 = (const float*)d_in[6];
  const float* Wm = (const float*)d_in[7];
  const float* bm = (const float*)d_in[8];
  const float* Wb = (const float*)d_in[9];
  const float* bb = (const float*)d_in[10];
  const float* Wr = (const float*)d_in[11];
  const float* br = (const float*)d_in[12];
  float* out = (float*)d_out;

  // workspace carve-up
  ushortT* P1  = (ushortT*)d_ws;                        // 2048*2560 bf16
  ushortT* P2  = P1 + (size_t)2048 * 2560;              // 2048*2560 bf16
  ushortT* WbP = P2 + (size_t)2048 * 2560;              // 64*2560 bf16
  ushortT* FP  = WbP + (size_t)64 * 2560;               // 128*2560 bf16
  float* ratio = (float*)(FP + (size_t)128 * 2560);     // 2048
  float* h1T   = ratio + NTOK;                          // 1024*2048 (col-major h1)

  setup_kernel<<<dim3(1812), dim3(256), 0, stream>>>(
      x, Wc, bc, Wm, bm, Wr, br, W1, b1, W2, b2, Wb, bb, FP, ratio, P1, P2, WbP);
  mm_kernel<1><<<dim3(512), dim3(256), 0, stream>>>(
      (const s8v*)FP, (const s8v*)P1, (const s8v*)WbP, x, nullptr, h1T);
  mm_kernel<2><<<dim3(512), dim3(256), 0, stream>>>(
      (const s8v*)FP, (const s8v*)P2, (const s8v*)WbP, h1T, ratio, out);
}